// Round 9
// baseline (915.359 us; speedup 1.0000x reference)
//
#include <hip/hip_runtime.h>
#include <hip/hip_bf16.h>

typedef short short8 __attribute__((ext_vector_type(8)));
typedef float f32x4 __attribute__((ext_vector_type(4)));

#define NB 32
#define NC 256
#define HW 56
#define HALO 58
#define NPIX 100352      // 32*56*56
#define PIXB 3136        // 56*56

__device__ inline void gl_lds16(const void* g, void* l) {
    __builtin_amdgcn_global_load_lds(
        (const __attribute__((address_space(1))) void*)g,
        (__attribute__((address_space(3))) void*)l, 16, 0, 0);
}

__device__ inline unsigned short sgn_bf16(float v) {
    return v > 0.f ? (unsigned short)0x3F80 : (v < 0.f ? (unsigned short)0xBF80 : (unsigned short)0);
}

// ---------------- zero only the halo borders of s_buf (3.7 MB instead of 55 MB memset)
__global__ void halo_zero(unsigned short* __restrict__ s) {
    const uint4 z = {0u, 0u, 0u, 0u};
    // 32 batches * 228 border cells * 32 uint4 per cell (256 ch * 2B = 512B)
    const int total = 32 * 228 * 32;
    for (int v = blockIdx.x * 256 + threadIdx.x; v < total; v += gridDim.x * 256) {
        int cellg = v >> 5, q = v & 31;
        int b = cellg / 228;
        int cell = cellg - b * 228;
        int y, xx;
        if (cell < 58)       { y = 0;          xx = cell; }
        else if (cell < 116) { y = 57;         xx = cell - 58; }
        else if (cell < 172) { y = cell - 115; xx = 0; }       // rows 1..56
        else                 { y = cell - 171; xx = 57; }      // rows 1..56
        *(uint4*)(s + (((size_t)b * HALO + y) * HALO + xx) * 256 + q * 8) = z;
    }
}

// ---------------- weight prep: sf[oc] = mean|w|, wsgn[oc][kh*3+kw][ic] = sign(w) as bf16
__global__ void wprep_kernel(const float* __restrict__ w, unsigned short* __restrict__ wsgn,
                             float* __restrict__ sf) {
    int oc = blockIdx.x;
    const float* wp = w + (size_t)oc * 2304;
    unsigned short* op = wsgn + (size_t)oc * 2304;
    float s = 0.f;
    for (int idx = threadIdx.x; idx < 2304; idx += 256) {
        float v = wp[idx];
        s += fabsf(v);
        int ic = idx / 9;
        int k = idx - ic * 9;
        op[k * 256 + ic] = sgn_bf16(v);
    }
    #pragma unroll
    for (int m = 32; m; m >>= 1) s += __shfl_xor(s, m);
    __shared__ float rs[4];
    if ((threadIdx.x & 63) == 0) rs[threadIdx.x >> 6] = s;
    __syncthreads();
    if (threadIdx.x == 0) sf[oc] = (rs[0] + rs[1] + rs[2] + rs[3]) * (1.f / 2304.f);
}

// ---------------- BN1 stats over x (NCHW): per-channel sum / sumsq
__global__ void bn_stats_x(const float* __restrict__ x, double* __restrict__ ssum,
                           double* __restrict__ ssq) {
    int bid = blockIdx.x;      // 2048 = 256 c * 8 bgroups
    int c = bid >> 3;
    int bg = bid & 7;
    float s = 0.f, q = 0.f;
    for (int b = bg * 4; b < bg * 4 + 4; ++b) {
        const float4* p = (const float4*)(x + ((size_t)(b * 256 + c)) * PIXB);
        for (int u = threadIdx.x; u < 784; u += 256) {
            float4 v = p[u];
            s += v.x + v.y + v.z + v.w;
            q += v.x * v.x + v.y * v.y + v.z * v.z + v.w * v.w;
        }
    }
    #pragma unroll
    for (int m = 32; m; m >>= 1) { s += __shfl_xor(s, m); q += __shfl_xor(q, m); }
    __shared__ float rs[4], rq[4];
    if ((threadIdx.x & 63) == 0) { rs[threadIdx.x >> 6] = s; rq[threadIdx.x >> 6] = q; }
    __syncthreads();
    if (threadIdx.x == 0) {
        atomicAdd(&ssum[c], (double)(rs[0] + rs[1] + rs[2] + rs[3]));
        atomicAdd(&ssq[c], (double)(rq[0] + rq[1] + rq[2] + rq[3]));
    }
}

// ---------------- finalize: scale = g*rsqrt(var+eps), shift = b - mean*scale
__global__ void bn_finalize(const double* __restrict__ ssum, const double* __restrict__ ssq,
                            const float* __restrict__ g, const float* __restrict__ b,
                            float* __restrict__ scale, float* __restrict__ shift) {
    int c = threadIdx.x;
    double m = ssum[c] * (1.0 / (double)NPIX);
    double v = ssq[c] * (1.0 / (double)NPIX) - m * m;
    double sc = (double)g[c] / sqrt(v + 1e-5);
    scale[c] = (float)sc;
    shift[c] = (float)((double)b[c] - m * sc);
}

// ---------------- sign1: x NCHW f32 -> s NHWC halo bf16 (sign(x*scale+shift))
__global__ void sign1_kernel(const float* __restrict__ x, const float* __restrict__ scale,
                             const float* __restrict__ shift, unsigned short* __restrict__ sdst) {
    __shared__ unsigned short lds[64 * 57];
    int bid = blockIdx.x;                  // 7168 = 32 b * 56 h * 4 cg
    int b = bid / 224;
    int rem = bid - b * 224;
    int h = rem >> 2;
    int cg = rem & 3;
    for (int idx = threadIdx.x; idx < 896; idx += 256) {    // 64 ch * 14 w4
        int cl = idx / 14;
        int w4 = idx - cl * 14;
        int c = cg * 64 + cl;
        float4 v = *(const float4*)(x + ((((size_t)b * 256 + c) * 56 + h) * 56) + w4 * 4);
        float sc = scale[c], sh = shift[c];
        lds[cl * 57 + w4 * 4 + 0] = sgn_bf16(v.x * sc + sh);
        lds[cl * 57 + w4 * 4 + 1] = sgn_bf16(v.y * sc + sh);
        lds[cl * 57 + w4 * 4 + 2] = sgn_bf16(v.z * sc + sh);
        lds[cl * 57 + w4 * 4 + 3] = sgn_bf16(v.w * sc + sh);
    }
    __syncthreads();
    unsigned short* dst = sdst + (((size_t)b * HALO + h + 1) * HALO + 1) * 256 + cg * 64;
    for (int u = threadIdx.x; u < 896; u += 256) {
        int w = u >> 4;
        int c4 = u & 15;
        ushort4 o;
        o.x = lds[(c4 * 4 + 0) * 57 + w];
        o.y = lds[(c4 * 4 + 1) * 57 + w];
        o.z = lds[(c4 * 4 + 2) * 57 + w];
        o.w = lds[(c4 * 4 + 3) * 57 + w];
        *(ushort4*)(dst + w * 256 + c4 * 4) = o;
    }
}

// ---------------- sign2: y [pix][oc] f32 -> s NHWC halo bf16 (fully coalesced)
__global__ void sign2_kernel(const float* __restrict__ y, const float* __restrict__ scale,
                             const float* __restrict__ shift, unsigned short* __restrict__ sdst) {
    int bid = blockIdx.x;                  // 1792 = 32 b * 56 h
    int b = bid / 56;
    int h = bid - b * 56;
    const float4* src = (const float4*)(y + (size_t)bid * 56 * 256);
    unsigned short* dst = sdst + (((size_t)b * HALO + h + 1) * HALO + 1) * 256;
    for (int u = threadIdx.x; u < 3584; u += 256) {
        int c0 = (u & 63) * 4;
        float4 v = src[u];
        float4 sc = *(const float4*)(scale + c0);
        float4 sh = *(const float4*)(shift + c0);
        ushort4 o;
        o.x = sgn_bf16(v.x * sc.x + sh.x);
        o.y = sgn_bf16(v.y * sc.y + sh.y);
        o.z = sgn_bf16(v.z * sc.z + sh.z);
        o.w = sgn_bf16(v.w * sc.w + sh.w);
        *(ushort4*)(dst + (size_t)u * 4) = o;
    }
}

// ---------------- conv: implicit GEMM, A = s (halo NHWC bf16 +-1), B = wsgn [oc][tap][ic]
// out y[pix][oc] = prelu(acc*sf[oc], alpha[oc]); fused BN stats (f64 atomics)
__global__ void conv_kernel(const unsigned short* __restrict__ sact,
                            const unsigned short* __restrict__ wsgn,
                            const float* __restrict__ sf, const float* __restrict__ alpha,
                            float* __restrict__ y, double* __restrict__ stat_sum,
                            double* __restrict__ stat_sumsq) {
    __shared__ char smem[16384];
    char* ldsA = smem;
    char* ldsB = smem + 8192;

    const int tid = threadIdx.x;
    const int lane = tid & 63;
    const int wave = tid >> 6;
    const int wm = wave >> 1, wn = wave & 1;

    const int bid = blockIdx.x;            // 1568 = 784 pixel tiles * 2 oc tiles
    const int oc0 = (bid & 1) * 128;
    const int pix0 = (bid >> 1) * 128;

    const char* sBytes = (const char*)sact;
    const char* wBytes = (const char*)wsgn;
    int aBase[2], bBase[2];
    #pragma unroll
    for (int j = 0; j < 2; ++j) {
        int pix = pix0 + j * 64 + lane;
        int b = pix / PIXB;
        int rem = pix - b * PIXB;
        int oh = rem / 56;
        int ow = rem - oh * 56;
        aBase[j] = ((b * HALO + oh) * HALO + ow) * 512;   // *256ch*2B (tap (0,0) base)
        bBase[j] = (oc0 + j * 64 + lane) * 4608;          // 9*256*2B
    }

    f32x4 acc[4][4];
    #pragma unroll
    for (int m = 0; m < 4; ++m)
        #pragma unroll
        for (int n = 0; n < 4; ++n) acc[m][n] = {0.f, 0.f, 0.f, 0.f};

    const int fi = lane & 15;
    const int fc = lane >> 4;
    const int aOffBase = fc * 2048 + (wm * 64 + fi) * 16;
    const int bOffBase = fc * 2048 + (wn * 64 + fi) * 16;
    char* ldsA_st = ldsA + wave * 2048;
    char* ldsB_st = ldsB + wave * 2048;
    const int kSt = wave * 16;

    #pragma unroll 1
    for (int tap = 0; tap < 9; ++tap) {
        const int tapOff = ((tap / 3) * HALO + (tap % 3)) * 512;
        const int wTap = tap * 512;
        #pragma unroll
        for (int sl = 0; sl < 8; ++sl) {
            const int aoff = tapOff + sl * 64 + kSt;
            const int woff = wTap + sl * 64 + kSt;
            gl_lds16(sBytes + aBase[0] + aoff, ldsA_st);
            gl_lds16(sBytes + aBase[1] + aoff, ldsA_st + 1024);
            gl_lds16(wBytes + bBase[0] + woff, ldsB_st);
            gl_lds16(wBytes + bBase[1] + woff, ldsB_st + 1024);
            __syncthreads();
            short8 af[4], bf[4];
            #pragma unroll
            for (int m = 0; m < 4; ++m) af[m] = *(const short8*)(ldsA + aOffBase + m * 256);
            #pragma unroll
            for (int n = 0; n < 4; ++n) bf[n] = *(const short8*)(ldsB + bOffBase + n * 256);
            #pragma unroll
            for (int m = 0; m < 4; ++m)
                #pragma unroll
                for (int n = 0; n < 4; ++n)
                    acc[m][n] = __builtin_amdgcn_mfma_f32_16x16x32_bf16(af[m], bf[n], acc[m][n], 0, 0, 0);
            __syncthreads();
        }
    }

    // epilogue: scale+prelu, LDS transpose to coalesced [pix][oc] writes, fused stats
    float sfv[4], alv[4];
    #pragma unroll
    for (int n = 0; n < 4; ++n) {
        int oc = oc0 + wn * 64 + n * 16 + fi;
        sfv[n] = sf[oc];
        alv[n] = alpha[oc];
    }

    float* trans = (float*)smem;            // [16][128]
    float* redS = (float*)(smem + 8192);    // [8][128]
    float* redQ = (float*)(smem + 12288);   // [8][128]
    const int cg = tid & 31;
    const int prw = tid >> 5;
    float ts[4] = {0.f, 0.f, 0.f, 0.f}, tq[4] = {0.f, 0.f, 0.f, 0.f};

    #pragma unroll
    for (int seg = 0; seg < 8; ++seg) {
        const int swm = seg >> 2, smi = seg & 3;
        if (wm == swm) {
            #pragma unroll
            for (int n = 0; n < 4; ++n) {
                f32x4 v = acc[smi][n];
                #pragma unroll
                for (int r = 0; r < 4; ++r) {
                    float val = v[r] * sfv[n];
                    val = val >= 0.f ? val : val * alv[n];
                    trans[(fc * 4 + r) * 128 + wn * 64 + n * 16 + fi] = val;
                }
            }
        }
        __syncthreads();
        #pragma unroll
        for (int i = 0; i < 2; ++i) {
            int p = prw + i * 8;
            f32x4 v = *(f32x4*)&trans[p * 128 + cg * 4];
            *(f32x4*)(y + (size_t)(pix0 + seg * 16 + p) * 256 + oc0 + cg * 4) = v;
            #pragma unroll
            for (int j = 0; j < 4; ++j) { ts[j] += v[j]; tq[j] += v[j] * v[j]; }
        }
        __syncthreads();
    }

    #pragma unroll
    for (int j = 0; j < 4; ++j) {
        redS[prw * 128 + cg * 4 + j] = ts[j];
        redQ[prw * 128 + cg * 4 + j] = tq[j];
    }
    __syncthreads();
    if (tid < 128) {
        float s = 0.f, q = 0.f;
        #pragma unroll
        for (int r = 0; r < 8; ++r) { s += redS[r * 128 + tid]; q += redQ[r * 128 + tid]; }
        atomicAdd(&stat_sum[oc0 + tid], (double)s);
        atomicAdd(&stat_sumsq[oc0 + tid], (double)q);
    }
}

// ---------------- final: out = prelu(z*scale3+shift3 + x, a3), [pix][oc] -> NCHW
__global__ void final_kernel(const float* __restrict__ z, const float* __restrict__ x,
                             const float* __restrict__ scale, const float* __restrict__ shift,
                             const float* __restrict__ a3, float* __restrict__ out) {
    __shared__ float lds[56 * 65];
    int bid = blockIdx.x;                  // 7168
    int b = bid / 224;
    int rem = bid - b * 224;
    int h = rem >> 2;
    int cg = rem & 3;
    for (int u = threadIdx.x; u < 896; u += 256) {
        int w = u >> 4;
        int c4 = u & 15;
        float4 v = *(const float4*)(z + ((size_t)(b * PIXB + h * 56 + w)) * 256 + cg * 64 + c4 * 4);
        int c = cg * 64 + c4 * 4;
        lds[w * 65 + c4 * 4 + 0] = v.x * scale[c + 0] + shift[c + 0];
        lds[w * 65 + c4 * 4 + 1] = v.y * scale[c + 1] + shift[c + 1];
        lds[w * 65 + c4 * 4 + 2] = v.z * scale[c + 2] + shift[c + 2];
        lds[w * 65 + c4 * 4 + 3] = v.w * scale[c + 3] + shift[c + 3];
    }
    __syncthreads();
    for (int u = threadIdx.x; u < 896; u += 256) {   // 64 ch * 14 w4
        int cl = u / 14;
        int w4 = u - cl * 14;
        int c = cg * 64 + cl;
        size_t off = ((((size_t)b * 256 + c) * 56 + h) * 56) + w4 * 4;
        float4 xv = *(const float4*)(x + off);
        float av = a3[c];
        float4 o;
        o.x = lds[(w4 * 4 + 0) * 65 + cl] + xv.x;
        o.y = lds[(w4 * 4 + 1) * 65 + cl] + xv.y;
        o.z = lds[(w4 * 4 + 2) * 65 + cl] + xv.z;
        o.w = lds[(w4 * 4 + 3) * 65 + cl] + xv.w;
        o.x = o.x >= 0.f ? o.x : o.x * av;
        o.y = o.y >= 0.f ? o.y : o.y * av;
        o.z = o.z >= 0.f ? o.z : o.z * av;
        o.w = o.w >= 0.f ? o.w : o.w * av;
        *(float4*)(out + off) = o;
    }
}

extern "C" void kernel_launch(void* const* d_in, const int* in_sizes, int n_in,
                              void* d_out, int out_size, void* d_ws, size_t ws_size,
                              hipStream_t stream) {
    const float* x = (const float*)d_in[0];
    const float* w1 = (const float*)d_in[1];
    const float* w2 = (const float*)d_in[2];
    const float* g1 = (const float*)d_in[3];
    const float* b1 = (const float*)d_in[4];
    const float* g2 = (const float*)d_in[5];
    const float* b2 = (const float*)d_in[6];
    const float* g3 = (const float*)d_in[7];
    const float* b3 = (const float*)d_in[8];
    const float* a1 = (const float*)d_in[9];
    const float* a2 = (const float*)d_in[10];
    const float* a3 = (const float*)d_in[11];
    float* out = (float*)d_out;

    char* ws = (char*)d_ws;
    size_t off = 0;
    auto alloc = [&](size_t bytes) {
        char* p = ws + off;
        off += (bytes + 255) & ~(size_t)255;
        return p;
    };
    const size_t SBUF_BYTES = (size_t)NB * HALO * HALO * 256 * 2;   // 55,115,776
    unsigned short* s_buf = (unsigned short*)alloc(SBUF_BYTES);
    float* y_buf = (float*)alloc((size_t)NPIX * 256 * 4);           // 102,760,448
    unsigned short* wsg1 = (unsigned short*)alloc(256 * 2304 * 2);
    unsigned short* wsg2 = (unsigned short*)alloc(256 * 2304 * 2);
    float* sf1 = (float*)alloc(1024);
    float* sf2 = (float*)alloc(1024);
    double* stats = (double*)alloc(6 * 256 * 8);
    float* scales = (float*)alloc(6 * 256 * 4);

    double *sum1 = stats, *q1 = stats + 256, *sum2 = stats + 512, *q2 = stats + 768,
           *sum3 = stats + 1024, *q3 = stats + 1280;
    float *scale1 = scales, *shift1 = scales + 256, *scale2 = scales + 512,
          *shift2 = scales + 768, *scale3 = scales + 1024, *shift3 = scales + 1280;

    hipMemsetAsync(stats, 0, 6 * 256 * 8, stream);

    halo_zero<<<256, 256, 0, stream>>>(s_buf);
    wprep_kernel<<<256, 256, 0, stream>>>(w1, wsg1, sf1);
    wprep_kernel<<<256, 256, 0, stream>>>(w2, wsg2, sf2);
    bn_stats_x<<<2048, 256, 0, stream>>>(x, sum1, q1);
    bn_finalize<<<1, 256, 0, stream>>>(sum1, q1, g1, b1, scale1, shift1);
    sign1_kernel<<<7168, 256, 0, stream>>>(x, scale1, shift1, s_buf);
    conv_kernel<<<1568, 256, 0, stream>>>(s_buf, wsg1, sf1, a1, y_buf, sum2, q2);
    bn_finalize<<<1, 256, 0, stream>>>(sum2, q2, g2, b2, scale2, shift2);
    sign2_kernel<<<1792, 256, 0, stream>>>(y_buf, scale2, shift2, s_buf);
    conv_kernel<<<1568, 256, 0, stream>>>(s_buf, wsg2, sf2, a2, y_buf, sum3, q3);
    bn_finalize<<<1, 256, 0, stream>>>(sum3, q3, g3, b3, scale3, shift3);
    final_kernel<<<7168, 256, 0, stream>>>(y_buf, x, scale3, shift3, a3, out);
}

// Round 13
// 900.711 us; speedup vs baseline: 1.0163x; 1.0163x over previous
//
#include <hip/hip_runtime.h>
#include <hip/hip_bf16.h>

typedef short short8 __attribute__((ext_vector_type(8)));
typedef float f32x4 __attribute__((ext_vector_type(4)));

#define NB 32
#define NC 256
#define HW 56
#define HALO 58
#define NPIX 100352      // 32*56*56
#define PIXB 3136        // 56*56

__device__ inline void gl_lds16(const void* g, void* l) {
    __builtin_amdgcn_global_load_lds(
        (const __attribute__((address_space(1))) void*)g,
        (__attribute__((address_space(3))) void*)l, 16, 0, 0);
}

__device__ inline unsigned short sgn_bf16(float v) {
    return v > 0.f ? (unsigned short)0x3F80 : (v < 0.f ? (unsigned short)0xBF80 : (unsigned short)0);
}

// ---------------- zero only the halo borders of s_buf (3.7 MB instead of 55 MB memset)
__global__ void halo_zero(unsigned short* __restrict__ s) {
    const uint4 z = {0u, 0u, 0u, 0u};
    const int total = 32 * 228 * 32;
    for (int v = blockIdx.x * 256 + threadIdx.x; v < total; v += gridDim.x * 256) {
        int cellg = v >> 5, q = v & 31;
        int b = cellg / 228;
        int cell = cellg - b * 228;
        int y, xx;
        if (cell < 58)       { y = 0;          xx = cell; }
        else if (cell < 116) { y = 57;         xx = cell - 58; }
        else if (cell < 172) { y = cell - 115; xx = 0; }       // rows 1..56
        else                 { y = cell - 171; xx = 57; }      // rows 1..56
        *(uint4*)(s + (((size_t)b * HALO + y) * HALO + xx) * 256 + q * 8) = z;
    }
}

// ---------------- weight prep: sf[oc] = mean|w|, wsgn[oc][kh*3+kw][ic] = sign(w) as bf16
__global__ void wprep_kernel(const float* __restrict__ w, unsigned short* __restrict__ wsgn,
                             float* __restrict__ sf) {
    int oc = blockIdx.x;
    const float* wp = w + (size_t)oc * 2304;
    unsigned short* op = wsgn + (size_t)oc * 2304;
    float s = 0.f;
    for (int idx = threadIdx.x; idx < 2304; idx += 256) {
        float v = wp[idx];
        s += fabsf(v);
        int ic = idx / 9;
        int k = idx - ic * 9;
        op[k * 256 + ic] = sgn_bf16(v);
    }
    #pragma unroll
    for (int m = 32; m; m >>= 1) s += __shfl_xor(s, m);
    __shared__ float rs[4];
    if ((threadIdx.x & 63) == 0) rs[threadIdx.x >> 6] = s;
    __syncthreads();
    if (threadIdx.x == 0) sf[oc] = (rs[0] + rs[1] + rs[2] + rs[3]) * (1.f / 2304.f);
}

// ---------------- BN1 stats over x (NCHW): per-channel sum / sumsq
__global__ void bn_stats_x(const float* __restrict__ x, double* __restrict__ ssum,
                           double* __restrict__ ssq) {
    int bid = blockIdx.x;      // 2048 = 256 c * 8 bgroups
    int c = bid >> 3;
    int bg = bid & 7;
    float s = 0.f, q = 0.f;
    for (int b = bg * 4; b < bg * 4 + 4; ++b) {
        const float4* p = (const float4*)(x + ((size_t)(b * 256 + c)) * PIXB);
        for (int u = threadIdx.x; u < 784; u += 256) {
            float4 v = p[u];
            s += v.x + v.y + v.z + v.w;
            q += v.x * v.x + v.y * v.y + v.z * v.z + v.w * v.w;
        }
    }
    #pragma unroll
    for (int m = 32; m; m >>= 1) { s += __shfl_xor(s, m); q += __shfl_xor(q, m); }
    __shared__ float rs[4], rq[4];
    if ((threadIdx.x & 63) == 0) { rs[threadIdx.x >> 6] = s; rq[threadIdx.x >> 6] = q; }
    __syncthreads();
    if (threadIdx.x == 0) {
        atomicAdd(&ssum[c], (double)(rs[0] + rs[1] + rs[2] + rs[3]));
        atomicAdd(&ssq[c], (double)(rq[0] + rq[1] + rq[2] + rq[3]));
    }
}

// ---------------- finalize: scale = g*rsqrt(var+eps), shift = b - mean*scale
__global__ void bn_finalize(const double* __restrict__ ssum, const double* __restrict__ ssq,
                            const float* __restrict__ g, const float* __restrict__ b,
                            float* __restrict__ scale, float* __restrict__ shift) {
    int c = threadIdx.x;
    double m = ssum[c] * (1.0 / (double)NPIX);
    double v = ssq[c] * (1.0 / (double)NPIX) - m * m;
    double sc = (double)g[c] / sqrt(v + 1e-5);
    scale[c] = (float)sc;
    shift[c] = (float)((double)b[c] - m * sc);
}

// ---------------- sign1: x NCHW f32 -> s NHWC halo bf16 (sign(x*scale+shift))
__global__ void sign1_kernel(const float* __restrict__ x, const float* __restrict__ scale,
                             const float* __restrict__ shift, unsigned short* __restrict__ sdst) {
    __shared__ unsigned short lds[64 * 57];
    int bid = blockIdx.x;                  // 7168 = 32 b * 56 h * 4 cg
    int b = bid / 224;
    int rem = bid - b * 224;
    int h = rem >> 2;
    int cg = rem & 3;
    for (int idx = threadIdx.x; idx < 896; idx += 256) {    // 64 ch * 14 w4
        int cl = idx / 14;
        int w4 = idx - cl * 14;
        int c = cg * 64 + cl;
        float4 v = *(const float4*)(x + ((((size_t)b * 256 + c) * 56 + h) * 56) + w4 * 4);
        float sc = scale[c], sh = shift[c];
        lds[cl * 57 + w4 * 4 + 0] = sgn_bf16(v.x * sc + sh);
        lds[cl * 57 + w4 * 4 + 1] = sgn_bf16(v.y * sc + sh);
        lds[cl * 57 + w4 * 4 + 2] = sgn_bf16(v.z * sc + sh);
        lds[cl * 57 + w4 * 4 + 3] = sgn_bf16(v.w * sc + sh);
    }
    __syncthreads();
    unsigned short* dst = sdst + (((size_t)b * HALO + h + 1) * HALO + 1) * 256 + cg * 64;
    for (int u = threadIdx.x; u < 896; u += 256) {
        int w = u >> 4;
        int c4 = u & 15;
        ushort4 o;
        o.x = lds[(c4 * 4 + 0) * 57 + w];
        o.y = lds[(c4 * 4 + 1) * 57 + w];
        o.z = lds[(c4 * 4 + 2) * 57 + w];
        o.w = lds[(c4 * 4 + 3) * 57 + w];
        *(ushort4*)(dst + w * 256 + c4 * 4) = o;
    }
}

// ---------------- sign2: y [pix][oc] f32 -> s NHWC halo bf16 (fully coalesced)
__global__ void sign2_kernel(const float* __restrict__ y, const float* __restrict__ scale,
                             const float* __restrict__ shift, unsigned short* __restrict__ sdst) {
    int bid = blockIdx.x;                  // 1792 = 32 b * 56 h
    int b = bid / 56;
    int h = bid - b * 56;
    const float4* src = (const float4*)(y + (size_t)bid * 56 * 256);
    unsigned short* dst = sdst + (((size_t)b * HALO + h + 1) * HALO + 1) * 256;
    for (int u = threadIdx.x; u < 3584; u += 256) {
        int c0 = (u & 63) * 4;
        float4 v = src[u];
        float4 sc = *(const float4*)(scale + c0);
        float4 sh = *(const float4*)(shift + c0);
        ushort4 o;
        o.x = sgn_bf16(v.x * sc.x + sh.x);
        o.y = sgn_bf16(v.y * sc.y + sh.y);
        o.z = sgn_bf16(v.z * sc.z + sh.z);
        o.w = sgn_bf16(v.w * sc.w + sh.w);
        *(ushort4*)(dst + (size_t)u * 4) = o;
    }
}

// ---------------- conv: implicit GEMM, A = s (halo NHWC bf16 +-1), B = wsgn [oc][tap][ic]
// 2-phase double-buffered staging (T3-mini) + bijective XCD chunk swizzle.
// out y[pix][oc] = prelu(acc*sf[oc], alpha[oc]); fused BN stats (f64 atomics)
__global__ void conv_kernel(const unsigned short* __restrict__ sact,
                            const unsigned short* __restrict__ wsgn,
                            const float* __restrict__ sf, const float* __restrict__ alpha,
                            float* __restrict__ y, double* __restrict__ stat_sum,
                            double* __restrict__ stat_sumsq) {
    __shared__ char smem[32768];           // [2][A:8K | B:8K] double buffer

    const int tid = threadIdx.x;
    const int lane = tid & 63;
    const int wave = tid >> 6;
    const int wm = wave >> 1, wn = wave & 1;

    // XCD chunk swizzle: blocks with blockIdx%8==x (same XCD under round-robin)
    // process a contiguous work chunk -> oc-pairs + neighbor pixel tiles share L2.
    const int bid = blockIdx.x;            // 1568 = 8 XCD chunks * 196 works
    const int work = (bid & 7) * 196 + (bid >> 3);
    const int oc0 = (work & 1) * 128;
    const int pix0 = (work >> 1) * 128;

    const char* sBytes = (const char*)sact;
    const char* wBytes = (const char*)wsgn;
    int aBase[2], bBase[2];
    #pragma unroll
    for (int j = 0; j < 2; ++j) {
        int pix = pix0 + j * 64 + lane;
        int b = pix / PIXB;
        int rem = pix - b * PIXB;
        int oh = rem / 56;
        int ow = rem - oh * 56;
        aBase[j] = ((b * HALO + oh) * HALO + ow) * 512;   // *256ch*2B (tap (0,0) base)
        bBase[j] = (oc0 + j * 64 + lane) * 4608;          // 9*256*2B
    }

    f32x4 acc[4][4];
    #pragma unroll
    for (int m = 0; m < 4; ++m)
        #pragma unroll
        for (int n = 0; n < 4; ++n) acc[m][n] = {0.f, 0.f, 0.f, 0.f};

    const int fi = lane & 15;
    const int fc = lane >> 4;
    const int aOffBase = fc * 2048 + (wm * 64 + fi) * 16;
    const int bOffBase = fc * 2048 + (wn * 64 + fi) * 16;
    const int stA = wave * 2048;           // per-wave staging slot
    const int kSt = wave * 16;

    // stage K-step 'it' (0..71 = tap*8+sl) into buffer half c
    auto STAGE = [&](int it, int c) {
        int tap = it >> 3, sl = it & 7;
        int ty = tap / 3, tx = tap - ty * 3;
        int aoff = (ty * HALO + tx) * 512 + sl * 64 + kSt;
        int woff = tap * 512 + sl * 64 + kSt;
        char* dstA = smem + c * 16384 + stA;
        char* dstB = smem + c * 16384 + 8192 + stA;
        gl_lds16(sBytes + aBase[0] + aoff, dstA);
        gl_lds16(sBytes + aBase[1] + aoff, dstA + 1024);
        gl_lds16(wBytes + bBase[0] + woff, dstB);
        gl_lds16(wBytes + bBase[1] + woff, dstB + 1024);
    };

    STAGE(0, 0);
    __syncthreads();                       // buf0 ready
    int cur = 0;
    #pragma unroll 1
    for (int it = 0; it < 72; ++it) {
        if (it < 71) STAGE(it + 1, cur ^ 1);   // async prefetch into other half
        const char* rdA = smem + cur * 16384;
        const char* rdB = rdA + 8192;
        short8 af[4], bf[4];
        #pragma unroll
        for (int m = 0; m < 4; ++m) af[m] = *(const short8*)(rdA + aOffBase + m * 256);
        #pragma unroll
        for (int n = 0; n < 4; ++n) bf[n] = *(const short8*)(rdB + bOffBase + n * 256);
        #pragma unroll
        for (int m = 0; m < 4; ++m)
            #pragma unroll
            for (int n = 0; n < 4; ++n)
                acc[m][n] = __builtin_amdgcn_mfma_f32_16x16x32_bf16(af[m], bf[n], acc[m][n], 0, 0, 0);
        __syncthreads();                   // drains prefetch (vmcnt) + own ds_reads (lgkm)
        cur ^= 1;
    }

    // epilogue: scale+prelu, LDS transpose to coalesced [pix][oc] writes, fused stats
    float sfv[4], alv[4];
    #pragma unroll
    for (int n = 0; n < 4; ++n) {
        int oc = oc0 + wn * 64 + n * 16 + fi;
        sfv[n] = sf[oc];
        alv[n] = alpha[oc];
    }

    float* trans = (float*)smem;            // [16][128]
    float* redS = (float*)(smem + 8192);    // [8][128]
    float* redQ = (float*)(smem + 12288);   // [8][128]
    const int cg = tid & 31;
    const int prw = tid >> 5;
    float ts[4] = {0.f, 0.f, 0.f, 0.f}, tq[4] = {0.f, 0.f, 0.f, 0.f};

    #pragma unroll
    for (int seg = 0; seg < 8; ++seg) {
        const int swm = seg >> 2, smi = seg & 3;
        if (wm == swm) {
            #pragma unroll
            for (int n = 0; n < 4; ++n) {
                f32x4 v = acc[smi][n];
                #pragma unroll
                for (int r = 0; r < 4; ++r) {
                    float val = v[r] * sfv[n];
                    val = val >= 0.f ? val : val * alv[n];
                    trans[(fc * 4 + r) * 128 + wn * 64 + n * 16 + fi] = val;
                }
            }
        }
        __syncthreads();
        #pragma unroll
        for (int i = 0; i < 2; ++i) {
            int p = prw + i * 8;
            f32x4 v = *(f32x4*)&trans[p * 128 + cg * 4];
            *(f32x4*)(y + (size_t)(pix0 + seg * 16 + p) * 256 + oc0 + cg * 4) = v;
            #pragma unroll
            for (int j = 0; j < 4; ++j) { ts[j] += v[j]; tq[j] += v[j] * v[j]; }
        }
        __syncthreads();
    }

    #pragma unroll
    for (int j = 0; j < 4; ++j) {
        redS[prw * 128 + cg * 4 + j] = ts[j];
        redQ[prw * 128 + cg * 4 + j] = tq[j];
    }
    __syncthreads();
    if (tid < 128) {
        float s = 0.f, q = 0.f;
        #pragma unroll
        for (int r = 0; r < 8; ++r) { s += redS[r * 128 + tid]; q += redQ[r * 128 + tid]; }
        atomicAdd(&stat_sum[oc0 + tid], (double)s);
        atomicAdd(&stat_sumsq[oc0 + tid], (double)q);
    }
}

// ---------------- final: out = prelu(z*scale3+shift3 + x, a3), [pix][oc] -> NCHW
__global__ void final_kernel(const float* __restrict__ z, const float* __restrict__ x,
                             const float* __restrict__ scale, const float* __restrict__ shift,
                             const float* __restrict__ a3, float* __restrict__ out) {
    __shared__ float lds[56 * 65];
    int bid = blockIdx.x;                  // 7168
    int b = bid / 224;
    int rem = bid - b * 224;
    int h = rem >> 2;
    int cg = rem & 3;
    for (int u = threadIdx.x; u < 896; u += 256) {
        int w = u >> 4;
        int c4 = u & 15;
        float4 v = *(const float4*)(z + ((size_t)(b * PIXB + h * 56 + w)) * 256 + cg * 64 + c4 * 4);
        int c = cg * 64 + c4 * 4;
        lds[w * 65 + c4 * 4 + 0] = v.x * scale[c + 0] + shift[c + 0];
        lds[w * 65 + c4 * 4 + 1] = v.y * scale[c + 1] + shift[c + 1];
        lds[w * 65 + c4 * 4 + 2] = v.z * scale[c + 2] + shift[c + 2];
        lds[w * 65 + c4 * 4 + 3] = v.w * scale[c + 3] + shift[c + 3];
    }
    __syncthreads();
    for (int u = threadIdx.x; u < 896; u += 256) {   // 64 ch * 14 w4
        int cl = u / 14;
        int w4 = u - cl * 14;
        int c = cg * 64 + cl;
        size_t off = ((((size_t)b * 256 + c) * 56 + h) * 56) + w4 * 4;
        float4 xv = *(const float4*)(x + off);
        float av = a3[c];
        float4 o;
        o.x = lds[(w4 * 4 + 0) * 65 + cl] + xv.x;
        o.y = lds[(w4 * 4 + 1) * 65 + cl] + xv.y;
        o.z = lds[(w4 * 4 + 2) * 65 + cl] + xv.z;
        o.w = lds[(w4 * 4 + 3) * 65 + cl] + xv.w;
        o.x = o.x >= 0.f ? o.x : o.x * av;
        o.y = o.y >= 0.f ? o.y : o.y * av;
        o.z = o.z >= 0.f ? o.z : o.z * av;
        o.w = o.w >= 0.f ? o.w : o.w * av;
        *(float4*)(out + off) = o;
    }
}

extern "C" void kernel_launch(void* const* d_in, const int* in_sizes, int n_in,
                              void* d_out, int out_size, void* d_ws, size_t ws_size,
                              hipStream_t stream) {
    const float* x = (const float*)d_in[0];
    const float* w1 = (const float*)d_in[1];
    const float* w2 = (const float*)d_in[2];
    const float* g1 = (const float*)d_in[3];
    const float* b1 = (const float*)d_in[4];
    const float* g2 = (const float*)d_in[5];
    const float* b2 = (const float*)d_in[6];
    const float* g3 = (const float*)d_in[7];
    const float* b3 = (const float*)d_in[8];
    const float* a1 = (const float*)d_in[9];
    const float* a2 = (const float*)d_in[10];
    const float* a3 = (const float*)d_in[11];
    float* out = (float*)d_out;

    char* ws = (char*)d_ws;
    size_t off = 0;
    auto alloc = [&](size_t bytes) {
        char* p = ws + off;
        off += (bytes + 255) & ~(size_t)255;
        return p;
    };
    const size_t SBUF_BYTES = (size_t)NB * HALO * HALO * 256 * 2;   // 55,115,776
    unsigned short* s_buf = (unsigned short*)alloc(SBUF_BYTES);
    float* y_buf = (float*)alloc((size_t)NPIX * 256 * 4);           // 102,760,448
    unsigned short* wsg1 = (unsigned short*)alloc(256 * 2304 * 2);
    unsigned short* wsg2 = (unsigned short*)alloc(256 * 2304 * 2);
    float* sf1 = (float*)alloc(1024);
    float* sf2 = (float*)alloc(1024);
    double* stats = (double*)alloc(6 * 256 * 8);
    float* scales = (float*)alloc(6 * 256 * 4);

    double *sum1 = stats, *q1 = stats + 256, *sum2 = stats + 512, *q2 = stats + 768,
           *sum3 = stats + 1024, *q3 = stats + 1280;
    float *scale1 = scales, *shift1 = scales + 256, *scale2 = scales + 512,
          *shift2 = scales + 768, *scale3 = scales + 1024, *shift3 = scales + 1280;

    hipMemsetAsync(stats, 0, 6 * 256 * 8, stream);

    halo_zero<<<256, 256, 0, stream>>>(s_buf);
    wprep_kernel<<<256, 256, 0, stream>>>(w1, wsg1, sf1);
    wprep_kernel<<<256, 256, 0, stream>>>(w2, wsg2, sf2);
    bn_stats_x<<<2048, 256, 0, stream>>>(x, sum1, q1);
    bn_finalize<<<1, 256, 0, stream>>>(sum1, q1, g1, b1, scale1, shift1);
    sign1_kernel<<<7168, 256, 0, stream>>>(x, scale1, shift1, s_buf);
    conv_kernel<<<1568, 256, 0, stream>>>(s_buf, wsg1, sf1, a1, y_buf, sum2, q2);
    bn_finalize<<<1, 256, 0, stream>>>(sum2, q2, g2, b2, scale2, shift2);
    sign2_kernel<<<1792, 256, 0, stream>>>(y_buf, scale2, shift2, s_buf);
    conv_kernel<<<1568, 256, 0, stream>>>(s_buf, wsg2, sf2, a2, y_buf, sum3, q3);
    bn_finalize<<<1, 256, 0, stream>>>(sum3, q3, g3, b3, scale3, shift3);
    final_kernel<<<7168, 256, 0, stream>>>(y_buf, x, scale3, shift3, a3, out);
}